// Round 13
// baseline (240.637 us; speedup 1.0000x reference)
//
#include <hip/hip_runtime.h>
#include <hip/hip_fp16.h>

#define F 128
#define F3 384
#define NRBF 20
#define NPB 16
#define CHUNK 64
#define PSN 32   // nodes per phi_stage block

typedef unsigned int u32;
typedef _Float16 half8 __attribute__((ext_vector_type(8)));
typedef float floatx4 __attribute__((ext_vector_type(4)));

__device__ __forceinline__ float2 uph(u32 u) {
    __half2 h = *(__half2*)&u;
    return __half22float2(h);
}
__device__ __forceinline__ u32 pkh(float a, float b) {
    __half2 h = __floats2half2_rn(a, b);
    return *(u32*)&h;
}

__device__ __forceinline__ float fdot2f(u32 a, u32 b, float c) {
#if defined(__has_builtin)
#if __has_builtin(__builtin_amdgcn_fdot2)
    typedef _Float16 h2 __attribute__((ext_vector_type(2)));
    return __builtin_amdgcn_fdot2(*(h2*)&a, *(h2*)&b, c, false);
#else
    float2 fa = uph(a), fb = uph(b);
    return fmaf(fa.x, fb.x, fmaf(fa.y, fb.y, c));
#endif
#else
    float2 fa = uph(a), fb = uph(b);
    return fmaf(fa.x, fb.x, fmaf(fa.y, fb.y, c));
#endif
}

// ---------------- A: merged {pack WrTh + pack Wh} ∥ {hist} (counts pre-zeroed by memset) ----------------
__global__ void prep2_kernel(const float* __restrict__ Wr,
                             const float* __restrict__ W1, const float* __restrict__ W2,
                             u32* __restrict__ WrTh, _Float16* __restrict__ Wh,
                             const int* __restrict__ idx_i, int* __restrict__ counts,
                             int n_edges, int PKB) {
    int blk = blockIdx.x, tid = threadIdx.x;
    if (blk >= PKB) {
        int e = (blk - PKB) * 256 + tid;
        if (e < n_edges) atomicAdd(&counts[idx_i[e]], 1);
        return;
    }
    int t = blk * 256 + tid;
    if (t < 10 * F3) {
        int rr = t / F3, f = t % F3;
        WrTh[rr * F3 + f] = pkh(Wr[f * NRBF + 2 * rr], Wr[f * NRBF + 2 * rr + 1]);
        return;
    }
    int u = t - 10 * F3;
    if (u < (F + F3) * F) {
        int n = u >> 7, k = u & (F - 1);
        float w = (n < F) ? W1[n * F + k] : W2[(size_t)(n - F) * F + k];
        Wh[u] = (_Float16)w;
    }
}

// ---------------- C: LDS-staged single-block exclusive scan ----------------
#define SCAN_T 1024
#define SCAN_MAXN 25600
__launch_bounds__(SCAN_T)
__global__ void scan_lds_kernel(const int* __restrict__ counts, int* __restrict__ row_start,
                                int* __restrict__ cursor, int n) {
    __shared__ int sbuf[SCAN_MAXN];
    __shared__ int partial[SCAN_T];
    int t = threadIdx.x;
    for (int i = t; i < n; i += SCAN_T) sbuf[i] = counts[i];
    __syncthreads();
    int C = (n + SCAN_T - 1) / SCAN_T;
    int beg = t * C, end = min(beg + C, n);
    int sum = 0;
    for (int i = beg; i < end; i++) sum += sbuf[i];
    partial[t] = sum;
    __syncthreads();
    for (int off = 1; off < SCAN_T; off <<= 1) {
        int v = (t >= off) ? partial[t - off] : 0;
        __syncthreads();
        partial[t] += v;
        __syncthreads();
    }
    int base = (t == 0) ? 0 : partial[t - 1];
    for (int i = beg; i < end; i++) { int c = sbuf[i]; sbuf[i] = base; base += c; }
    __syncthreads();
    for (int i = t; i < n; i += SCAN_T) { int v = sbuf[i]; row_start[i] = v; cursor[i] = v; }
    if (t == SCAN_T - 1) row_start[n] = partial[SCAN_T - 1];
}

__launch_bounds__(1024)
__global__ void scan_kernel(const int* __restrict__ counts, int* __restrict__ row_start,
                            int* __restrict__ cursor, int n) {
    __shared__ int partial[1024];
    int t = threadIdx.x;
    int C = (n + 1023) / 1024;
    int beg = t * C, end = min(beg + C, n);
    int sum = 0;
    for (int i = beg; i < end; i++) sum += counts[i];
    partial[t] = sum;
    __syncthreads();
    for (int off = 1; off < 1024; off <<= 1) {
        int v = (t >= off) ? partial[t - off] : 0;
        __syncthreads();
        partial[t] += v;
        __syncthreads();
    }
    int base = (t == 0) ? 0 : partial[t - 1];
    for (int i = beg; i < end; i++) {
        int c = counts[i];
        row_start[i] = base; cursor[i] = base; base += c;
    }
    if (t == 1023) row_start[n] = partial[1023];
}

// ---------------- D: scatter edge ids (4 B/edge) ----------------
__global__ void scatter_kernel(const int* __restrict__ idx_i, int* __restrict__ cursor,
                               int* __restrict__ edge_order, int n_edges) {
    int e = blockIdx.x * blockDim.x + threadIdx.x;
    if (e < n_edges) {
        int p = atomicAdd(&cursor[idx_i[e]], 1);
        edge_order[p] = e;
    }
}

// ---------------- E: phi_stage — MFMA phi + vf permute, LDS-staged, coalesced gbuf writes ----------------
__launch_bounds__(128)
__global__ void phi_stage_kernel(const float* __restrict__ sf,
                                 const _Float16* __restrict__ Wh,
                                 const float* __restrict__ b1, const float* __restrict__ b2,
                                 const float* __restrict__ vf, __half* __restrict__ gbufh,
                                 int n_nodes) {
    __shared__ __align__(16) _Float16 stage[PSN * 768];
    _Float16 (*hl)[16][136] = reinterpret_cast<_Float16 (*)[16][136]>(stage);

    int tid = threadIdx.x;
    int lane = tid & 63;
    int wv = tid >> 6;
    int col = lane & 15;
    int kg = lane >> 4;
    int base = blockIdx.x * PSN;
    int row0 = base + wv * 16;

    half8 a1[4];
#pragma unroll
    for (int kb = 0; kb < 4; kb++) {
        int rr = row0 + col;
        if (rr >= n_nodes) rr = n_nodes - 1;
        const float4* xp = (const float4*)(sf + (size_t)rr * F + kb * 32 + kg * 8);
        float4 x0 = xp[0], x1 = xp[1];
        half8 a;
        a[0] = (_Float16)x0.x; a[1] = (_Float16)x0.y; a[2] = (_Float16)x0.z; a[3] = (_Float16)x0.w;
        a[4] = (_Float16)x1.x; a[5] = (_Float16)x1.y; a[6] = (_Float16)x1.z; a[7] = (_Float16)x1.w;
        a1[kb] = a;
    }

    floatx4 acc[8];
#pragma unroll
    for (int nt = 0; nt < 8; nt++) acc[nt] = (floatx4){0.f, 0.f, 0.f, 0.f};
#pragma unroll
    for (int nt = 0; nt < 8; nt++) {
#pragma unroll
        for (int kb = 0; kb < 4; kb++) {
            half8 b = *(const half8*)(Wh + (size_t)(nt * 16 + col) * F + kb * 32 + kg * 8);
            acc[nt] = __builtin_amdgcn_mfma_f32_16x16x32_f16(a1[kb], b, acc[nt], 0, 0, 0);
        }
    }
#pragma unroll
    for (int nt = 0; nt < 8; nt++) {
        int f1 = nt * 16 + col;
        float bb = b1[f1];
#pragma unroll
        for (int r = 0; r < 4; r++) {
            float v = acc[nt][r] + bb;
            float s = v / (1.f + __expf(-v));
            hl[wv][kg * 4 + r][f1] = (_Float16)s;
        }
    }
    __syncthreads();

    half8 a2[4];
#pragma unroll
    for (int kb = 0; kb < 4; kb++)
        a2[kb] = *(const half8*)&hl[wv][col][kb * 32 + kg * 8];
    __syncthreads();

#pragma unroll
    for (int c = 0; c < 3; c++) {
#pragma unroll
        for (int nt = 0; nt < 8; nt++) acc[nt] = (floatx4){0.f, 0.f, 0.f, 0.f};
#pragma unroll
        for (int nt = 0; nt < 8; nt++) {
#pragma unroll
            for (int kb = 0; kb < 4; kb++) {
                half8 b = *(const half8*)(Wh + (size_t)(F + c * 128 + nt * 16 + col) * F + kb * 32 + kg * 8);
                acc[nt] = __builtin_amdgcn_mfma_f32_16x16x32_f16(a2[kb], b, acc[nt], 0, 0, 0);
            }
        }
#pragma unroll
        for (int nt = 0; nt < 8; nt++) {
            int f2 = c * 128 + nt * 16 + col;
            float bb = b2[f2];
            int slot = (f2 & 63) * 12 + ((f2 >> 6) & 1) * 6 + (f2 >> 7);
#pragma unroll
            for (int r = 0; r < 4; r++) {
                int nl = wv * 16 + kg * 4 + r;
                stage[nl * 768 + slot] = (_Float16)(acc[nt][r] + bb);
            }
        }
    }

    for (int idx = tid; idx < PSN * 64; idx += 128) {
        int nl = idx >> 6, ln = idx & 63;
        int node = base + nl;
        if (node < n_nodes) {
            const float* v = vf + (size_t)node * F3;
            _Float16* s = stage + nl * 768 + ln * 12;
            s[3]  = (_Float16)v[ln * 3 + 0];
            s[4]  = (_Float16)v[ln * 3 + 1];
            s[5]  = (_Float16)v[ln * 3 + 2];
            s[9]  = (_Float16)v[(ln + 64) * 3 + 0];
            s[10] = (_Float16)v[(ln + 64) * 3 + 1];
            s[11] = (_Float16)v[(ln + 64) * 3 + 2];
        }
    }
    __syncthreads();

    const uint4* s4 = (const uint4*)stage;
    uint4* g4 = (uint4*)gbufh + (size_t)base * 96;
    for (int t = tid; t < PSN * 96; t += 128) {
        int node = base + t / 96;
        if (node < n_nodes) g4[t] = s4[t];
    }
}

// ---------------- F: gather7 — records built in LDS from raw arrays via edge_order ----------------
__launch_bounds__(256)
__global__ void gather7_kernel(const int* __restrict__ idx_j,
                               const float* __restrict__ rel_dir, const float* __restrict__ rdc,
                               const float* __restrict__ rbf,
                               const float* __restrict__ sf, const float* __restrict__ vf,
                               const u32* __restrict__ WrTh, const float* __restrict__ br,
                               const u32* __restrict__ gbuf,
                               const int* __restrict__ row_start, const int* __restrict__ edge_order,
                               float* __restrict__ out_s, float* __restrict__ out_v,
                               int n_nodes) {
    __shared__ u32 lsm[4][CHUNK * 16];
    int tid = threadIdx.x;
    int lane = tid & 63;
    int wvid = tid >> 6;
    int w = wvid & 1;
    int node = blockIdx.x * 2 + (wvid >> 1);
    if (node >= n_nodes) return;
    u32* lds = lsm[wvid];

    int fb = lane + 64 * w;
    u32 wrpk[3][10];
    float brv[3];
#pragma unroll
    for (int k = 0; k < 3; k++) {
        brv[k] = br[fb + 128 * k];
#pragma unroll
        for (int rr = 0; rr < 10; rr++)
            wrpk[k][rr] = WrTh[rr * F3 + fb + 128 * k];
    }

    float acc_s = 0.f, av0 = 0.f, av1 = 0.f, av2 = 0.f;
    int beg = row_start[node];
    int end = row_start[node + 1];

    for (int cb = beg; cb < end; cb += CHUNK) {
        int cnt = min(CHUNK, end - cb);

        // stage: build this chunk's 64-B records directly in LDS (lane l -> edge cb+l)
        if (lane < cnt) {
            int e = edge_order[cb + lane];
            int j = idx_j[e];
            float rd = rdc[e];
            float d0 = rel_dir[e * 3 + 0], d1 = rel_dir[e * 3 + 1], d2 = rel_dir[e * 3 + 2];
            const float4* rp = (const float4*)(rbf + (size_t)e * NRBF);   // 80-B rows, 16-B aligned
            float4 r0 = rp[0], r1 = rp[1], r2 = rp[2], r3 = rp[3], r4 = rp[4];
            uint4* rec = (uint4*)(lds + lane * 16);
            rec[0] = make_uint4((u32)j, __float_as_uint(rd), __float_as_uint(d0), __float_as_uint(d1));
            rec[1] = make_uint4(__float_as_uint(d2), pkh(r0.x, r0.y), pkh(r0.z, r0.w), pkh(r1.x, r1.y));
            rec[2] = make_uint4(pkh(r1.z, r1.w), pkh(r2.x, r2.y), pkh(r2.z, r2.w), pkh(r3.x, r3.y));
            rec[3] = make_uint4(pkh(r3.z, r3.w), pkh(r4.x, r4.y), pkh(r4.z, r4.w), 0u);
        }

        auto issueL = [&](u32& g0, u32& g1, u32& g2, int m) {
            if (m < cnt) {
                int j = (int)lds[m * 16];
                const u32* gp = gbuf + (size_t)j * 384 + lane * 6 + w * 3;
                g0 = gp[0]; g1 = gp[1]; g2 = gp[2];
            }
        };
        auto computeE = [&](u32 g0, u32 g1, u32 g2, int m) {
            const uint4* q = (const uint4*)(lds + m * 16);
            uint4 q0 = q[0], q1 = q[1], q2 = q[2], q3 = q[3];
            float rd = __uint_as_float(q0.y);
            float dx = __uint_as_float(q0.z);
            float dy = __uint_as_float(q0.w);
            float dz = __uint_as_float(q1.x);
            u32 rbu[10] = { q1.y, q1.z, q1.w, q2.x, q2.y, q2.z, q2.w, q3.x, q3.y, q3.z };
            float W0 = brv[0], W1f = brv[1], W2f = brv[2];
#pragma unroll
            for (int rr = 0; rr < 10; rr++) {
                W0  = fdot2f(rbu[rr], wrpk[0][rr], W0);
                W1f = fdot2f(rbu[rr], wrpk[1][rr], W1f);
                W2f = fdot2f(rbu[rr], wrpk[2][rr], W2f);
            }
            float2 p01  = uph(g0);
            float2 p2v0 = uph(g1);
            float2 v12  = uph(g2);
            float pw0 = W0  * rd * p01.x;
            float pw1 = W1f * rd * p01.y;
            float pw2 = W2f * rd * p2v0.x;
            acc_s += pw1;
            av0 += p2v0.y * pw0 + pw2 * dx;
            av1 += v12.x  * pw0 + pw2 * dy;
            av2 += v12.y  * pw0 + pw2 * dz;
        };

        u32 A0, A1, A2, B0, B1, B2, C0, C1, C2, D0, D1, D2;
        issueL(A0, A1, A2, 0); issueL(B0, B1, B2, 1);
        issueL(C0, C1, C2, 2); issueL(D0, D1, D2, 3);
        int m = 0;
        while (true) {
            if (m >= cnt) break; computeE(A0, A1, A2, m); m++; issueL(A0, A1, A2, m + 3);
            if (m >= cnt) break; computeE(B0, B1, B2, m); m++; issueL(B0, B1, B2, m + 3);
            if (m >= cnt) break; computeE(C0, C1, C2, m); m++; issueL(C0, C1, C2, m + 3);
            if (m >= cnt) break; computeE(D0, D1, D2, m); m++; issueL(D0, D1, D2, m + 3);
        }
    }

    out_s[(size_t)node * F + fb] = sf[(size_t)node * F + fb] + acc_s;
    const float* vfi = vf + (size_t)node * F3 + fb * 3;
    float* ovi = out_v + (size_t)node * F3 + fb * 3;
    ovi[0] = vfi[0] + av0;
    ovi[1] = vfi[1] + av1;
    ovi[2] = vfi[2] + av2;
}

// ---------------- tiny-ws fallback ----------------
__global__ void transpose_wr(const float* __restrict__ Wr, float* __restrict__ WrT) {
    int idx = blockIdx.x * blockDim.x + threadIdx.x;
    if (idx < F3 * NRBF) {
        int f = idx / NRBF, r = idx % NRBF;
        WrT[r * F3 + f] = Wr[idx];
    }
}

__global__ void init_out(const float* __restrict__ sf, const float* __restrict__ vf,
                         float* __restrict__ out, int n_scalar, int n_total) {
    int i = blockIdx.x * blockDim.x + threadIdx.x;
    int n4 = n_total >> 2;
    if (i < n4) {
        float4 v;
        int base = i << 2;
        if (base < n_scalar) v = ((const float4*)sf)[i];
        else                 v = ((const float4*)vf)[i - (n_scalar >> 2)];
        ((float4*)out)[i] = v;
    }
}

__launch_bounds__(256)
__global__ void phi32_kernel(const float* __restrict__ sf,
                             const float* __restrict__ W1, const float* __restrict__ b1,
                             const float* __restrict__ W2, const float* __restrict__ b2,
                             float* __restrict__ phi, int n_nodes) {
    __shared__ float xs[NPB][F];
    __shared__ float hs[NPB][F];
    int tid = threadIdx.x;
    int nb = blockIdx.x * NPB;
    for (int t = tid; t < NPB * F / 4; t += 256) {
        int n  = t / (F / 4);
        int k4 = t % (F / 4);
        float4 v = make_float4(0.f, 0.f, 0.f, 0.f);
        if (nb + n < n_nodes) v = ((const float4*)(sf + (size_t)(nb + n) * F))[k4];
        ((float4*)&xs[n][0])[k4] = v;
    }
    __syncthreads();
    {
        int f = tid & (F - 1);
        int half_ = tid >> 7;
        float acc[8];
#pragma unroll
        for (int nn = 0; nn < 8; nn++) acc[nn] = 0.f;
        const float* w1row = W1 + (size_t)f * F;
        for (int k = 0; k < F; k++) {
            float w = w1row[k];
#pragma unroll
            for (int nn = 0; nn < 8; nn++)
                acc[nn] += xs[half_ * 8 + nn][k] * w;
        }
        float b = b1[f];
#pragma unroll
        for (int nn = 0; nn < 8; nn++) {
            float v = acc[nn] + b;
            hs[half_ * 8 + nn][f] = v / (1.f + __expf(-v));
        }
    }
    __syncthreads();
    for (int f = tid; f < F3; f += 256) {
        float acc[NPB];
#pragma unroll
        for (int n = 0; n < NPB; n++) acc[n] = 0.f;
        const float* w2row = W2 + (size_t)f * F;
        for (int k = 0; k < F; k++) {
            float w = w2row[k];
#pragma unroll
            for (int n = 0; n < NPB; n++)
                acc[n] += hs[n][k] * w;
        }
        float b = b2[f];
        for (int n = 0; n < NPB; n++)
            if (nb + n < n_nodes)
                phi[(size_t)(nb + n) * F3 + f] = acc[n] + b;
    }
}

__launch_bounds__(256)
__global__ void edge_kernel(const int* __restrict__ idx_i, const int* __restrict__ idx_j,
                            const float* __restrict__ rel_dir, const float* __restrict__ rdc,
                            const float* __restrict__ rbf,
                            const float* __restrict__ vf,
                            const float* __restrict__ WrT, const float* __restrict__ br,
                            const float* __restrict__ phi,
                            float* __restrict__ out_s, float* __restrict__ out_v,
                            int n_edges) {
    int lane = threadIdx.x & 63;
    int e = (int)((blockIdx.x * (unsigned)blockDim.x + threadIdx.x) >> 6);
    if (e >= n_edges) return;
    int i = idx_i[e], j = idx_j[e];
    float rd = rdc[e];
    float d0 = rel_dir[e * 3 + 0], d1 = rel_dir[e * 3 + 1], d2 = rel_dir[e * 3 + 2];
    float rb[NRBF];
#pragma unroll
    for (int r = 0; r < NRBF; r++) rb[r] = rbf[(size_t)e * NRBF + r];
    const float* pj = phi + (size_t)j * F3;
    float pw[6];
#pragma unroll
    for (int q = 0; q < 6; q++) {
        int f = lane + 64 * q;
        float acc = br[f];
#pragma unroll
        for (int r = 0; r < NRBF; r++)
            acc += rb[r] * WrT[r * F3 + f];
        pw[q] = acc * rd * pj[f];
    }
    atomicAdd(&out_s[(size_t)i * F + lane],       pw[2]);
    atomicAdd(&out_s[(size_t)i * F + lane + 64],  pw[3]);
    const float* vfj = vf + (size_t)j * F * 3;
    float* ovi = out_v + (size_t)i * F * 3;
#pragma unroll
    for (int h = 0; h < 2; h++) {
        int f = lane + 64 * h;
        float vv = pw[h];
        float vs = pw[4 + h];
        atomicAdd(&ovi[f * 3 + 0], vfj[f * 3 + 0] * vv + vs * d0);
        atomicAdd(&ovi[f * 3 + 1], vfj[f * 3 + 1] * vv + vs * d1);
        atomicAdd(&ovi[f * 3 + 2], vfj[f * 3 + 2] * vv + vs * d2);
    }
}

extern "C" void kernel_launch(void* const* d_in, const int* in_sizes, int n_in,
                              void* d_out, int out_size, void* d_ws, size_t ws_size,
                              hipStream_t stream) {
    const int*   idx_i   = (const int*)d_in[0];
    const int*   idx_j   = (const int*)d_in[1];
    const float* rel_dir = (const float*)d_in[2];
    const float* rdc     = (const float*)d_in[3];
    const float* rbf     = (const float*)d_in[4];
    const float* sf      = (const float*)d_in[5];
    const float* vf      = (const float*)d_in[6];
    const float* W1      = (const float*)d_in[7];
    const float* b1      = (const float*)d_in[8];
    const float* W2      = (const float*)d_in[9];
    const float* b2      = (const float*)d_in[10];
    const float* Wr      = (const float*)d_in[11];
    const float* br      = (const float*)d_in[12];

    int E = in_sizes[0];
    int N = in_sizes[5] / F;

    float* out_s = (float*)d_out;
    float* out_v = out_s + (size_t)N * F;

    // ---- v7 layout: edge_order only (no record buffer) ----
    size_t off = 0;
    auto slab = [&](size_t bytes) { size_t o = off; off = (off + bytes + 255) & ~(size_t)255; return o; };
    size_t o_wrth = slab((size_t)10 * F3 * sizeof(u32));
    size_t o_wh   = slab((size_t)(F + F3) * F * sizeof(_Float16));
    size_t o_gbuf = slab((size_t)N * 768 * sizeof(__half));
    size_t o_cnt  = slab((size_t)N * sizeof(int));
    size_t o_row  = slab((size_t)(N + 1) * sizeof(int));
    size_t o_ord  = slab((size_t)E * sizeof(int));
    size_t need_v7 = off;

    int pack_threads = 10 * F3 + (F + F3) * F;
    int PKB = (pack_threads + 255) / 256;
    int HB  = (E + 255) / 256;
    int PSB = (N + PSN - 1) / PSN;

    if (ws_size >= need_v7) {
        u32*      WrTh      = (u32*)((char*)d_ws + o_wrth);
        _Float16* Wh        = (_Float16*)((char*)d_ws + o_wh);
        __half*   gbufh     = (__half*)((char*)d_ws + o_gbuf);
        u32*      gbuf      = (u32*)gbufh;
        int*      counts    = (int*)((char*)d_ws + o_cnt);
        int*      cursor    = counts;
        int*      row_start = (int*)((char*)d_ws + o_row);
        int*      edge_ord  = (int*)((char*)d_ws + o_ord);

        hipMemsetAsync(counts, 0, (size_t)N * sizeof(int), stream);
        prep2_kernel<<<PKB + HB, 256, 0, stream>>>(Wr, W1, W2, WrTh, Wh, idx_i, counts, E, PKB);
        if (N <= SCAN_MAXN)
            scan_lds_kernel<<<1, SCAN_T, 0, stream>>>(counts, row_start, cursor, N);
        else
            scan_kernel<<<1, 1024, 0, stream>>>(counts, row_start, cursor, N);
        scatter_kernel<<<HB, 256, 0, stream>>>(idx_i, cursor, edge_ord, E);
        phi_stage_kernel<<<PSB, 128, 0, stream>>>(sf, Wh, b1, b2, vf, gbufh, N);
        gather7_kernel<<<(N + 1) / 2, 256, 0, stream>>>(idx_j, rel_dir, rdc, rbf, sf, vf,
                                                        WrTh, br, gbuf, row_start, edge_ord,
                                                        out_s, out_v, N);
    } else {
        size_t off2 = 0;
        auto slab2 = [&](size_t bytes) { size_t o = off2; off2 = (off2 + bytes + 255) & ~(size_t)255; return o; };
        size_t f_wrt = slab2((size_t)F3 * NRBF * sizeof(float));
        size_t f_phi = slab2((size_t)N * F3 * sizeof(float));
        float* WrT = (float*)((char*)d_ws + f_wrt);
        float* phi = (float*)((char*)d_ws + f_phi);

        int n_scalar = N * F;
        int n_total  = N * F * 4;
        init_out<<<(n_total / 4 + 255) / 256, 256, 0, stream>>>(sf, vf, (float*)d_out, n_scalar, n_total);
        transpose_wr<<<(F3 * NRBF + 255) / 256, 256, 0, stream>>>(Wr, WrT);
        phi32_kernel<<<(N + NPB - 1) / NPB, 256, 0, stream>>>(sf, W1, b1, W2, b2, phi, N);
        edge_kernel<<<(E + 3) / 4, 256, 0, stream>>>(idx_i, idx_j, rel_dir, rdc, rbf,
                                                     vf, WrT, br, phi, out_s, out_v, E);
    }
}

// Round 14
// 205.789 us; speedup vs baseline: 1.1693x; 1.1693x over previous
//
#include <hip/hip_runtime.h>
#include <hip/hip_fp16.h>

#define F 128
#define F3 384
#define NRBF 20
#define NPB 16
#define CHUNK 64
#define PSN 32   // nodes per phi_stage block

typedef unsigned int u32;
typedef _Float16 half8 __attribute__((ext_vector_type(8)));
typedef float floatx4 __attribute__((ext_vector_type(4)));

__device__ __forceinline__ float2 uph(u32 u) {
    __half2 h = *(__half2*)&u;
    return __half22float2(h);
}
__device__ __forceinline__ u32 pkh(float a, float b) {
    __half2 h = __floats2half2_rn(a, b);
    return *(u32*)&h;
}

__device__ __forceinline__ float fdot2f(u32 a, u32 b, float c) {
#if defined(__has_builtin)
#if __has_builtin(__builtin_amdgcn_fdot2)
    typedef _Float16 h2 __attribute__((ext_vector_type(2)));
    return __builtin_amdgcn_fdot2(*(h2*)&a, *(h2*)&b, c, false);
#else
    float2 fa = uph(a), fb = uph(b);
    return fmaf(fa.x, fb.x, fmaf(fa.y, fb.y, c));
#endif
#else
    float2 fa = uph(a), fb = uph(b);
    return fmaf(fa.x, fb.x, fmaf(fa.y, fb.y, c));
#endif
}

// ---------------- A: merged {pack WrTh + pack Wh} ∥ {hist} (counts pre-zeroed by memset) ----------------
__global__ void prep2_kernel(const float* __restrict__ Wr,
                             const float* __restrict__ W1, const float* __restrict__ W2,
                             u32* __restrict__ WrTh, _Float16* __restrict__ Wh,
                             const int* __restrict__ idx_i, int* __restrict__ counts,
                             int n_edges, int PKB) {
    int blk = blockIdx.x, tid = threadIdx.x;
    if (blk >= PKB) {
        int e = (blk - PKB) * 256 + tid;
        if (e < n_edges) atomicAdd(&counts[idx_i[e]], 1);
        return;
    }
    int t = blk * 256 + tid;
    if (t < 10 * F3) {
        int rr = t / F3, f = t % F3;
        WrTh[rr * F3 + f] = pkh(Wr[f * NRBF + 2 * rr], Wr[f * NRBF + 2 * rr + 1]);
        return;
    }
    int u = t - 10 * F3;
    if (u < (F + F3) * F) {
        int n = u >> 7, k = u & (F - 1);
        float w = (n < F) ? W1[n * F + k] : W2[(size_t)(n - F) * F + k];
        Wh[u] = (_Float16)w;
    }
}

// ---------------- C: LDS-staged single-block exclusive scan ----------------
#define SCAN_T 1024
#define SCAN_MAXN 25600
__launch_bounds__(SCAN_T)
__global__ void scan_lds_kernel(const int* __restrict__ counts, int* __restrict__ row_start,
                                int* __restrict__ cursor, int n) {
    __shared__ int sbuf[SCAN_MAXN];
    __shared__ int partial[SCAN_T];
    int t = threadIdx.x;
    for (int i = t; i < n; i += SCAN_T) sbuf[i] = counts[i];
    __syncthreads();
    int C = (n + SCAN_T - 1) / SCAN_T;
    int beg = t * C, end = min(beg + C, n);
    int sum = 0;
    for (int i = beg; i < end; i++) sum += sbuf[i];
    partial[t] = sum;
    __syncthreads();
    for (int off = 1; off < SCAN_T; off <<= 1) {
        int v = (t >= off) ? partial[t - off] : 0;
        __syncthreads();
        partial[t] += v;
        __syncthreads();
    }
    int base = (t == 0) ? 0 : partial[t - 1];
    for (int i = beg; i < end; i++) { int c = sbuf[i]; sbuf[i] = base; base += c; }
    __syncthreads();
    for (int i = t; i < n; i += SCAN_T) { int v = sbuf[i]; row_start[i] = v; cursor[i] = v; }
    if (t == SCAN_T - 1) row_start[n] = partial[SCAN_T - 1];
}

__launch_bounds__(1024)
__global__ void scan_kernel(const int* __restrict__ counts, int* __restrict__ row_start,
                            int* __restrict__ cursor, int n) {
    __shared__ int partial[1024];
    int t = threadIdx.x;
    int C = (n + 1023) / 1024;
    int beg = t * C, end = min(beg + C, n);
    int sum = 0;
    for (int i = beg; i < end; i++) sum += counts[i];
    partial[t] = sum;
    __syncthreads();
    for (int off = 1; off < 1024; off <<= 1) {
        int v = (t >= off) ? partial[t - off] : 0;
        __syncthreads();
        partial[t] += v;
        __syncthreads();
    }
    int base = (t == 0) ? 0 : partial[t - 1];
    for (int i = beg; i < end; i++) {
        int c = counts[i];
        row_start[i] = base; cursor[i] = base; base += c;
    }
    if (t == 1023) row_start[n] = partial[1023];
}

// ---------------- D: merged {phi_stage (MFMA+LDS, coalesced writes)} ∥ {build_records} ----------------
// blocks [0, PSB): phi for 32 nodes each; blocks [PSB, ...): build 128 edges each.
__launch_bounds__(128)
__global__ void stage_build_kernel(const float* __restrict__ sf,
                                   const _Float16* __restrict__ Wh,
                                   const float* __restrict__ b1, const float* __restrict__ b2,
                                   const float* __restrict__ vf, __half* __restrict__ gbufh,
                                   const int* __restrict__ idx_i, const int* __restrict__ idx_j,
                                   const float* __restrict__ rel_dir, const float* __restrict__ rdc,
                                   const float* __restrict__ rbf,
                                   int* __restrict__ cursor, u32* __restrict__ recs,
                                   int n_nodes, int n_edges, int PSB) {
    __shared__ __align__(16) _Float16 stage[PSN * 768];   // 48 KB
    int blk = blockIdx.x, tid = threadIdx.x;

    if (blk >= PSB) {
        // ---- build_records: 128 edges per block ----
        int e = (blk - PSB) * 128 + tid;
        if (e >= n_edges) return;
        int p = atomicAdd(&cursor[idx_i[e]], 1);
        u32 r[16];
        r[0] = (u32)idx_j[e];
        r[1] = __float_as_uint(rdc[e]);
        r[2] = __float_as_uint(rel_dir[e * 3 + 0]);
        r[3] = __float_as_uint(rel_dir[e * 3 + 1]);
        r[4] = __float_as_uint(rel_dir[e * 3 + 2]);
        const float* rb = rbf + (size_t)e * NRBF;
#pragma unroll
        for (int t2 = 0; t2 < 10; t2++) r[5 + t2] = pkh(rb[2 * t2], rb[2 * t2 + 1]);
        r[15] = 0;
        float4* dst = (float4*)(recs + (size_t)p * 16);
        const float4* src = (const float4*)r;
        dst[0] = src[0]; dst[1] = src[1]; dst[2] = src[2]; dst[3] = src[3];
        return;
    }

    // ---- phi_stage ----
    _Float16 (*hl)[16][136] = reinterpret_cast<_Float16 (*)[16][136]>(stage);
    int lane = tid & 63;
    int wv = tid >> 6;
    int col = lane & 15;
    int kg = lane >> 4;
    int base = blk * PSN;
    int row0 = base + wv * 16;

    half8 a1[4];
#pragma unroll
    for (int kb = 0; kb < 4; kb++) {
        int rr = row0 + col;
        if (rr >= n_nodes) rr = n_nodes - 1;
        const float4* xp = (const float4*)(sf + (size_t)rr * F + kb * 32 + kg * 8);
        float4 x0 = xp[0], x1 = xp[1];
        half8 a;
        a[0] = (_Float16)x0.x; a[1] = (_Float16)x0.y; a[2] = (_Float16)x0.z; a[3] = (_Float16)x0.w;
        a[4] = (_Float16)x1.x; a[5] = (_Float16)x1.y; a[6] = (_Float16)x1.z; a[7] = (_Float16)x1.w;
        a1[kb] = a;
    }

    floatx4 acc[8];
#pragma unroll
    for (int nt = 0; nt < 8; nt++) acc[nt] = (floatx4){0.f, 0.f, 0.f, 0.f};
#pragma unroll
    for (int nt = 0; nt < 8; nt++) {
#pragma unroll
        for (int kb = 0; kb < 4; kb++) {
            half8 b = *(const half8*)(Wh + (size_t)(nt * 16 + col) * F + kb * 32 + kg * 8);
            acc[nt] = __builtin_amdgcn_mfma_f32_16x16x32_f16(a1[kb], b, acc[nt], 0, 0, 0);
        }
    }
#pragma unroll
    for (int nt = 0; nt < 8; nt++) {
        int f1 = nt * 16 + col;
        float bb = b1[f1];
#pragma unroll
        for (int r = 0; r < 4; r++) {
            float v = acc[nt][r] + bb;
            float s = v / (1.f + __expf(-v));
            hl[wv][kg * 4 + r][f1] = (_Float16)s;
        }
    }
    __syncthreads();

    half8 a2[4];
#pragma unroll
    for (int kb = 0; kb < 4; kb++)
        a2[kb] = *(const half8*)&hl[wv][col][kb * 32 + kg * 8];
    __syncthreads();

#pragma unroll
    for (int c = 0; c < 3; c++) {
#pragma unroll
        for (int nt = 0; nt < 8; nt++) acc[nt] = (floatx4){0.f, 0.f, 0.f, 0.f};
#pragma unroll
        for (int nt = 0; nt < 8; nt++) {
#pragma unroll
            for (int kb = 0; kb < 4; kb++) {
                half8 b = *(const half8*)(Wh + (size_t)(F + c * 128 + nt * 16 + col) * F + kb * 32 + kg * 8);
                acc[nt] = __builtin_amdgcn_mfma_f32_16x16x32_f16(a2[kb], b, acc[nt], 0, 0, 0);
            }
        }
#pragma unroll
        for (int nt = 0; nt < 8; nt++) {
            int f2 = c * 128 + nt * 16 + col;
            float bb = b2[f2];
            int slot = (f2 & 63) * 12 + ((f2 >> 6) & 1) * 6 + (f2 >> 7);
#pragma unroll
            for (int r = 0; r < 4; r++) {
                int nl = wv * 16 + kg * 4 + r;
                stage[nl * 768 + slot] = (_Float16)(acc[nt][r] + bb);
            }
        }
    }

    for (int idx = tid; idx < PSN * 64; idx += 128) {
        int nl = idx >> 6, ln = idx & 63;
        int node = base + nl;
        if (node < n_nodes) {
            const float* v = vf + (size_t)node * F3;
            _Float16* s = stage + nl * 768 + ln * 12;
            s[3]  = (_Float16)v[ln * 3 + 0];
            s[4]  = (_Float16)v[ln * 3 + 1];
            s[5]  = (_Float16)v[ln * 3 + 2];
            s[9]  = (_Float16)v[(ln + 64) * 3 + 0];
            s[10] = (_Float16)v[(ln + 64) * 3 + 1];
            s[11] = (_Float16)v[(ln + 64) * 3 + 2];
        }
    }
    __syncthreads();

    const uint4* s4 = (const uint4*)stage;
    uint4* g4 = (uint4*)gbufh + (size_t)base * 96;
    for (int t = tid; t < PSN * 96; t += 128) {
        int node = base + t / 96;
        if (node < n_nodes) g4[t] = s4[t];
    }
}

// ---------------- E: gather5 — exact R8/R12 version ----------------
__launch_bounds__(256)
__global__ void gather5_kernel(const float* __restrict__ sf, const float* __restrict__ vf,
                               const u32* __restrict__ WrTh, const float* __restrict__ br,
                               const u32* __restrict__ gbuf, const u32* __restrict__ recs,
                               const int* __restrict__ row_start,
                               float* __restrict__ out_s, float* __restrict__ out_v,
                               int n_nodes) {
    __shared__ u32 lsm[4][CHUNK * 16];
    int tid = threadIdx.x;
    int lane = tid & 63;
    int wvid = tid >> 6;
    int w = wvid & 1;
    int node = blockIdx.x * 2 + (wvid >> 1);
    if (node >= n_nodes) return;
    u32* lds = lsm[wvid];

    int fb = lane + 64 * w;
    u32 wrpk[3][10];
    float brv[3];
#pragma unroll
    for (int k = 0; k < 3; k++) {
        brv[k] = br[fb + 128 * k];
#pragma unroll
        for (int rr = 0; rr < 10; rr++)
            wrpk[k][rr] = WrTh[rr * F3 + fb + 128 * k];
    }

    float acc_s = 0.f, av0 = 0.f, av1 = 0.f, av2 = 0.f;
    int beg = row_start[node];
    int end = row_start[node + 1];

    for (int cb = beg; cb < end; cb += CHUNK) {
        int cnt = min(CHUNK, end - cb);
        {
            const float4* src = (const float4*)(recs + (size_t)cb * 16);
            int nf4 = cnt * 4;
            for (int t = lane; t < nf4; t += 64)
                ((float4*)lds)[t] = src[t];
        }

        auto issueL = [&](u32& g0, u32& g1, u32& g2, int m) {
            if (m < cnt) {
                int j = (int)lds[m * 16];
                const u32* gp = gbuf + (size_t)j * 384 + lane * 6 + w * 3;
                g0 = gp[0]; g1 = gp[1]; g2 = gp[2];
            }
        };
        auto computeE = [&](u32 g0, u32 g1, u32 g2, int m) {
            const uint4* q = (const uint4*)(lds + m * 16);
            uint4 q0 = q[0], q1 = q[1], q2 = q[2], q3 = q[3];
            float rd = __uint_as_float(q0.y);
            float dx = __uint_as_float(q0.z);
            float dy = __uint_as_float(q0.w);
            float dz = __uint_as_float(q1.x);
            u32 rbu[10] = { q1.y, q1.z, q1.w, q2.x, q2.y, q2.z, q2.w, q3.x, q3.y, q3.z };
            float W0 = brv[0], W1f = brv[1], W2f = brv[2];
#pragma unroll
            for (int rr = 0; rr < 10; rr++) {
                W0  = fdot2f(rbu[rr], wrpk[0][rr], W0);
                W1f = fdot2f(rbu[rr], wrpk[1][rr], W1f);
                W2f = fdot2f(rbu[rr], wrpk[2][rr], W2f);
            }
            float2 p01  = uph(g0);
            float2 p2v0 = uph(g1);
            float2 v12  = uph(g2);
            float pw0 = W0  * rd * p01.x;
            float pw1 = W1f * rd * p01.y;
            float pw2 = W2f * rd * p2v0.x;
            acc_s += pw1;
            av0 += p2v0.y * pw0 + pw2 * dx;
            av1 += v12.x  * pw0 + pw2 * dy;
            av2 += v12.y  * pw0 + pw2 * dz;
        };

        u32 A0, A1, A2, B0, B1, B2, C0, C1, C2, D0, D1, D2;
        issueL(A0, A1, A2, 0); issueL(B0, B1, B2, 1);
        issueL(C0, C1, C2, 2); issueL(D0, D1, D2, 3);
        int m = 0;
        while (true) {
            if (m >= cnt) break; computeE(A0, A1, A2, m); m++; issueL(A0, A1, A2, m + 3);
            if (m >= cnt) break; computeE(B0, B1, B2, m); m++; issueL(B0, B1, B2, m + 3);
            if (m >= cnt) break; computeE(C0, C1, C2, m); m++; issueL(C0, C1, C2, m + 3);
            if (m >= cnt) break; computeE(D0, D1, D2, m); m++; issueL(D0, D1, D2, m + 3);
        }
    }

    out_s[(size_t)node * F + fb] = sf[(size_t)node * F + fb] + acc_s;
    const float* vfi = vf + (size_t)node * F3 + fb * 3;
    float* ovi = out_v + (size_t)node * F3 + fb * 3;
    ovi[0] = vfi[0] + av0;
    ovi[1] = vfi[1] + av1;
    ovi[2] = vfi[2] + av2;
}

// ---------------- tiny-ws fallback ----------------
__global__ void transpose_wr(const float* __restrict__ Wr, float* __restrict__ WrT) {
    int idx = blockIdx.x * blockDim.x + threadIdx.x;
    if (idx < F3 * NRBF) {
        int f = idx / NRBF, r = idx % NRBF;
        WrT[r * F3 + f] = Wr[idx];
    }
}

__global__ void init_out(const float* __restrict__ sf, const float* __restrict__ vf,
                         float* __restrict__ out, int n_scalar, int n_total) {
    int i = blockIdx.x * blockDim.x + threadIdx.x;
    int n4 = n_total >> 2;
    if (i < n4) {
        float4 v;
        int base = i << 2;
        if (base < n_scalar) v = ((const float4*)sf)[i];
        else                 v = ((const float4*)vf)[i - (n_scalar >> 2)];
        ((float4*)out)[i] = v;
    }
}

__launch_bounds__(256)
__global__ void phi32_kernel(const float* __restrict__ sf,
                             const float* __restrict__ W1, const float* __restrict__ b1,
                             const float* __restrict__ W2, const float* __restrict__ b2,
                             float* __restrict__ phi, int n_nodes) {
    __shared__ float xs[NPB][F];
    __shared__ float hs[NPB][F];
    int tid = threadIdx.x;
    int nb = blockIdx.x * NPB;
    for (int t = tid; t < NPB * F / 4; t += 256) {
        int n  = t / (F / 4);
        int k4 = t % (F / 4);
        float4 v = make_float4(0.f, 0.f, 0.f, 0.f);
        if (nb + n < n_nodes) v = ((const float4*)(sf + (size_t)(nb + n) * F))[k4];
        ((float4*)&xs[n][0])[k4] = v;
    }
    __syncthreads();
    {
        int f = tid & (F - 1);
        int half_ = tid >> 7;
        float acc[8];
#pragma unroll
        for (int nn = 0; nn < 8; nn++) acc[nn] = 0.f;
        const float* w1row = W1 + (size_t)f * F;
        for (int k = 0; k < F; k++) {
            float w = w1row[k];
#pragma unroll
            for (int nn = 0; nn < 8; nn++)
                acc[nn] += xs[half_ * 8 + nn][k] * w;
        }
        float b = b1[f];
#pragma unroll
        for (int nn = 0; nn < 8; nn++) {
            float v = acc[nn] + b;
            hs[half_ * 8 + nn][f] = v / (1.f + __expf(-v));
        }
    }
    __syncthreads();
    for (int f = tid; f < F3; f += 256) {
        float acc[NPB];
#pragma unroll
        for (int n = 0; n < NPB; n++) acc[n] = 0.f;
        const float* w2row = W2 + (size_t)f * F;
        for (int k = 0; k < F; k++) {
            float w = w2row[k];
#pragma unroll
            for (int n = 0; n < NPB; n++)
                acc[n] += hs[n][k] * w;
        }
        float b = b2[f];
        for (int n = 0; n < NPB; n++)
            if (nb + n < n_nodes)
                phi[(size_t)(nb + n) * F3 + f] = acc[n] + b;
    }
}

__launch_bounds__(256)
__global__ void edge_kernel(const int* __restrict__ idx_i, const int* __restrict__ idx_j,
                            const float* __restrict__ rel_dir, const float* __restrict__ rdc,
                            const float* __restrict__ rbf,
                            const float* __restrict__ vf,
                            const float* __restrict__ WrT, const float* __restrict__ br,
                            const float* __restrict__ phi,
                            float* __restrict__ out_s, float* __restrict__ out_v,
                            int n_edges) {
    int lane = threadIdx.x & 63;
    int e = (int)((blockIdx.x * (unsigned)blockDim.x + threadIdx.x) >> 6);
    if (e >= n_edges) return;
    int i = idx_i[e], j = idx_j[e];
    float rd = rdc[e];
    float d0 = rel_dir[e * 3 + 0], d1 = rel_dir[e * 3 + 1], d2 = rel_dir[e * 3 + 2];
    float rb[NRBF];
#pragma unroll
    for (int r = 0; r < NRBF; r++) rb[r] = rbf[(size_t)e * NRBF + r];
    const float* pj = phi + (size_t)j * F3;
    float pw[6];
#pragma unroll
    for (int q = 0; q < 6; q++) {
        int f = lane + 64 * q;
        float acc = br[f];
#pragma unroll
        for (int r = 0; r < NRBF; r++)
            acc += rb[r] * WrT[r * F3 + f];
        pw[q] = acc * rd * pj[f];
    }
    atomicAdd(&out_s[(size_t)i * F + lane],       pw[2]);
    atomicAdd(&out_s[(size_t)i * F + lane + 64],  pw[3]);
    const float* vfj = vf + (size_t)j * F * 3;
    float* ovi = out_v + (size_t)i * F * 3;
#pragma unroll
    for (int h = 0; h < 2; h++) {
        int f = lane + 64 * h;
        float vv = pw[h];
        float vs = pw[4 + h];
        atomicAdd(&ovi[f * 3 + 0], vfj[f * 3 + 0] * vv + vs * d0);
        atomicAdd(&ovi[f * 3 + 1], vfj[f * 3 + 1] * vv + vs * d1);
        atomicAdd(&ovi[f * 3 + 2], vfj[f * 3 + 2] * vv + vs * d2);
    }
}

extern "C" void kernel_launch(void* const* d_in, const int* in_sizes, int n_in,
                              void* d_out, int out_size, void* d_ws, size_t ws_size,
                              hipStream_t stream) {
    const int*   idx_i   = (const int*)d_in[0];
    const int*   idx_j   = (const int*)d_in[1];
    const float* rel_dir = (const float*)d_in[2];
    const float* rdc     = (const float*)d_in[3];
    const float* rbf     = (const float*)d_in[4];
    const float* sf      = (const float*)d_in[5];
    const float* vf      = (const float*)d_in[6];
    const float* W1      = (const float*)d_in[7];
    const float* b1      = (const float*)d_in[8];
    const float* W2      = (const float*)d_in[9];
    const float* b2      = (const float*)d_in[10];
    const float* Wr      = (const float*)d_in[11];
    const float* br      = (const float*)d_in[12];

    int E = in_sizes[0];
    int N = in_sizes[5] / F;

    float* out_s = (float*)d_out;
    float* out_v = out_s + (size_t)N * F;

    // ---- v8 layout: records path (R12 layout) ----
    size_t off = 0;
    auto slab = [&](size_t bytes) { size_t o = off; off = (off + bytes + 255) & ~(size_t)255; return o; };
    size_t o_wrth = slab((size_t)10 * F3 * sizeof(u32));
    size_t o_wh   = slab((size_t)(F + F3) * F * sizeof(_Float16));
    size_t o_gbuf = slab((size_t)N * 768 * sizeof(__half));
    size_t o_cnt  = slab((size_t)N * sizeof(int));
    size_t o_row  = slab((size_t)(N + 1) * sizeof(int));
    size_t o_rec  = slab((size_t)E * 64);
    size_t need_v8 = off;

    int pack_threads = 10 * F3 + (F + F3) * F;
    int PKB = (pack_threads + 255) / 256;
    int HB  = (E + 255) / 256;
    int PSB = (N + PSN - 1) / PSN;
    int BB  = (E + 127) / 128;

    if (ws_size >= need_v8) {
        u32*      WrTh      = (u32*)((char*)d_ws + o_wrth);
        _Float16* Wh        = (_Float16*)((char*)d_ws + o_wh);
        __half*   gbufh     = (__half*)((char*)d_ws + o_gbuf);
        u32*      gbuf      = (u32*)gbufh;
        int*      counts    = (int*)((char*)d_ws + o_cnt);
        int*      cursor    = counts;
        int*      row_start = (int*)((char*)d_ws + o_row);
        u32*      recs      = (u32*)((char*)d_ws + o_rec);

        hipMemsetAsync(counts, 0, (size_t)N * sizeof(int), stream);
        prep2_kernel<<<PKB + HB, 256, 0, stream>>>(Wr, W1, W2, WrTh, Wh, idx_i, counts, E, PKB);
        if (N <= SCAN_MAXN)
            scan_lds_kernel<<<1, SCAN_T, 0, stream>>>(counts, row_start, cursor, N);
        else
            scan_kernel<<<1, 1024, 0, stream>>>(counts, row_start, cursor, N);
        stage_build_kernel<<<PSB + BB, 128, 0, stream>>>(sf, Wh, b1, b2, vf, gbufh,
                                                         idx_i, idx_j, rel_dir, rdc, rbf,
                                                         cursor, recs, N, E, PSB);
        gather5_kernel<<<(N + 1) / 2, 256, 0, stream>>>(sf, vf, WrTh, br, gbuf, recs,
                                                        row_start, out_s, out_v, N);
    } else {
        size_t off2 = 0;
        auto slab2 = [&](size_t bytes) { size_t o = off2; off2 = (off2 + bytes + 255) & ~(size_t)255; return o; };
        size_t f_wrt = slab2((size_t)F3 * NRBF * sizeof(float));
        size_t f_phi = slab2((size_t)N * F3 * sizeof(float));
        float* WrT = (float*)((char*)d_ws + f_wrt);
        float* phi = (float*)((char*)d_ws + f_phi);

        int n_scalar = N * F;
        int n_total  = N * F * 4;
        init_out<<<(n_total / 4 + 255) / 256, 256, 0, stream>>>(sf, vf, (float*)d_out, n_scalar, n_total);
        transpose_wr<<<(F3 * NRBF + 255) / 256, 256, 0, stream>>>(Wr, WrT);
        phi32_kernel<<<(N + NPB - 1) / NPB, 256, 0, stream>>>(sf, W1, b1, W2, b2, phi, N);
        edge_kernel<<<(E + 3) / 4, 256, 0, stream>>>(idx_i, idx_j, rel_dir, rdc, rbf,
                                                     vf, WrT, br, phi, out_s, out_v, E);
    }
}